// Round 10
// baseline (542.662 us; speedup 1.0000x reference)
//
#include <hip/hip_runtime.h>
#include <cstdint>
#include <cstddef>

#define TT    4096          // sequence length
#define NB    4             // batch
#define DIMV  1024
#define MTOT  (NB*TT)       // 16384 rows
#define KK    1024          // GEMM K
#define NCOL  4096          // GEMM N (4*DIM)
#define NCH   64            // scan chunks
#define CL    (TT/NCH)      // 64 steps per chunk

#define BM 256
#define BN 128
#define BK 32

typedef _Float16 half8 __attribute__((ext_vector_type(8)));
typedef float    f32x4 __attribute__((ext_vector_type(4)));
typedef __attribute__((address_space(1))) void GV;
typedef __attribute__((address_space(3))) void LV;

__device__ __forceinline__ void gload16(const void* g, void* l) {
    __builtin_amdgcn_global_load_lds((GV*)g, (LV*)l, 16, 0, 0);
}

// fast activations: v_exp_f32 / v_log_f32 based, overflow-safe
__device__ __forceinline__ float ftanh(float x) {          // 1 - 2/(e^2x+1)
    return 1.0f - 2.0f / (__expf(2.0f * x) + 1.0f);
}
__device__ __forceinline__ float fsig(float x) {
    return 1.0f / (1.0f + __expf(-x));
}
__device__ __forceinline__ float fsoftplus(float x) {
    return fmaxf(x, 0.0f) + __logf(1.0f + __expf(-fabsf(x)));
}

// ---------- conversions ----------
__global__ __launch_bounds__(256) void k_cvt_x(const float* __restrict__ x,
                                               _Float16* __restrict__ Xs) {
    int idx = blockIdx.x * 256 + threadIdx.x;   // [16384][1024]
    Xs[idx] = (_Float16)x[idx];
}

// W [1024][4096] fp32 -> Wt [4096][1024] fp16 (transposed, N-major for B^T GEMM)
__global__ __launch_bounds__(256) void k_cvt_w(const float* __restrict__ W,
                                               _Float16* __restrict__ Wt) {
    __shared__ float tile[32][33];
    int tx = threadIdx.x & 31, ty = threadIdx.x >> 5;   // 32 x 8
    int nb = blockIdx.x * 32, kb = blockIdx.y * 32;
#pragma unroll
    for (int j = 0; j < 32; j += 8)
        tile[ty + j][tx] = W[(size_t)(kb + ty + j) * NCOL + nb + tx];
    __syncthreads();
#pragma unroll
    for (int j = 0; j < 32; j += 8)
        Wt[(size_t)(nb + ty + j) * KK + kb + tx] = (_Float16)tile[tx][ty + j];
}

// ---------- GEMM + fused gate activations ----------
// A = Xs [16384][1024] f16, Bt = Wt [4096][1024] f16 (both row-major).
// 256x128 tile, BK=32, 4 waves (2M x 2N), wave-tile 128x64 (8x4 frags of
// 16x16x32, acc 128 VGPR). R6's proven 2-phase double-buffer schedule:
// issue next tile's global_load_lds BEFORE the current tile's ds_read+MFMA,
// ONE __syncthreads per K-tile. LDS = 2 x (A 16KB + B 8KB) = 48 KB ->
// 3 blocks/CU (12 waves/CU): cross-block overlap hides the barrier drains
// that capped the 1-block/CU 256x256 variants at MfmaUtil ~25% (R6-R9).
// Anti-conflict swizzle (rule 21, 0 conflicts measured): phys 16B slot s of
// row r holds logical slot s ^ ((r>>1)&3); linear LDS dest, pre-swizzled
// global src, same XOR on read.
__global__ __launch_bounds__(256) void k_gemm_gates(
    const _Float16* __restrict__ Xs, const _Float16* __restrict__ Wt,
    const float* __restrict__ bias, const float* __restrict__ ibias,
    _Float16* __restrict__ gi, float* __restrict__ gf,
    _Float16* __restrict__ go, _Float16* __restrict__ gtz)
{
    __shared__ __align__(16) _Float16 Al0[BM * BK];   // 16 KB
    __shared__ __align__(16) _Float16 Al1[BM * BK];   // 16 KB
    __shared__ __align__(16) _Float16 Bl0[BN * BK];   //  8 KB
    __shared__ __align__(16) _Float16 Bl1[BN * BK];   //  8 KB
    const int tid  = threadIdx.x;       // 0..255
    const int lane = tid & 63;
    const int wave = tid >> 6;          // 0..3

    // bijective XCD swizzle (nwg = 2048, multiple of 8)
    const int nwg = 32 * 64;
    int id = blockIdx.y * 32 + blockIdx.x;
    id = (id & 7) * (nwg >> 3) + (id >> 3);
    const int m0 = (id >> 5) * BM;      // 64 m-panels
    const int n0 = (id & 31) * BN;      // 32 n-panels
    const int wm = (wave >> 1) * 128;   // 0 | 128
    const int wn = (wave & 1) * 64;     // 0 | 64

    // staging: thread stages rows r0+64k (16B chunks), phys slot tid&3.
    // A: k=0..3 (256 rows), B: k=0..1 (128 rows). 64 even -> same swizzle.
    const int r0  = tid >> 2;                        // 0..63
    const int swz = (tid & 3) ^ ((r0 >> 1) & 3);
    const _Float16* aSrc = Xs + (size_t)(m0 + r0) * KK + swz * 8;
    const _Float16* bSrc = Wt + (size_t)(n0 + r0) * KK + swz * 8;

    f32x4 acc[8][4] = {};
    const int lr = lane & 15;
    const int ps = ((lane >> 4) ^ ((lr >> 1) & 3)) * 8;   // phys slot on read

#define STAGE(ABUF, BBUF, kkc)                                             \
    gload16(aSrc + (kkc),                    &ABUF[tid * 8]);              \
    gload16(aSrc + (size_t) 64 * KK + (kkc), &ABUF[tid * 8 + 2048]);       \
    gload16(aSrc + (size_t)128 * KK + (kkc), &ABUF[tid * 8 + 4096]);       \
    gload16(aSrc + (size_t)192 * KK + (kkc), &ABUF[tid * 8 + 6144]);       \
    gload16(bSrc + (kkc),                    &BBUF[tid * 8]);              \
    gload16(bSrc + (size_t) 64 * KK + (kkc), &BBUF[tid * 8 + 2048]);

#define COMPUTE(ABUF, BBUF)                                                \
    {                                                                      \
        half8 af[8], bf[4];                                                \
        _Pragma("unroll")                                                  \
        for (int mi = 0; mi < 8; ++mi)                                     \
            af[mi] = *(const half8*)&ABUF[(wm + mi * 16 + lr) * BK + ps];  \
        _Pragma("unroll")                                                  \
        for (int nj = 0; nj < 4; ++nj)                                     \
            bf[nj] = *(const half8*)&BBUF[(wn + nj * 16 + lr) * BK + ps];  \
        __builtin_amdgcn_s_setprio(1);                                     \
        _Pragma("unroll")                                                  \
        for (int mi = 0; mi < 8; ++mi)                                     \
            _Pragma("unroll")                                              \
            for (int nj = 0; nj < 4; ++nj)                                 \
                acc[mi][nj] = __builtin_amdgcn_mfma_f32_16x16x32_f16(      \
                    af[mi], bf[nj], acc[mi][nj], 0, 0, 0);                 \
        __builtin_amdgcn_s_setprio(0);                                     \
    }

    // prologue: tile 0 -> buf0
    STAGE(Al0, Bl0, 0)
    __syncthreads();
#pragma unroll 1
    for (int t = 0; t < 15; ++t) {
        const int k1 = (2 * t + 1) * BK, k2 = (2 * t + 2) * BK;
        STAGE(Al1, Bl1, k1)                 // issue tile 2t+1 loads
        COMPUTE(Al0, Bl0)                   // compute tile 2t
        __syncthreads();                    // buf1 landed; buf0 reads done
        STAGE(Al0, Bl0, k2)                 // issue tile 2t+2 loads
        COMPUTE(Al1, Bl1)                   // compute tile 2t+1
        __syncthreads();
    }
    {
        const int k1 = 31 * BK;
        STAGE(Al1, Bl1, k1)
        COMPUTE(Al0, Bl0)                   // tile 30
        __syncthreads();
        COMPUTE(Al1, Bl1)                   // tile 31
    }
#undef STAGE
#undef COMPUTE

    // epilogue: C/D layout col=lane&15, row=(lane>>4)*4+reg  [m89-verified]
    const int gate = n0 >> 10;          // block-uniform (BN=128 divides 1024)
#pragma unroll
    for (int mi = 0; mi < 8; ++mi) {
        const int rowb = m0 + wm + mi * 16 + (lane >> 4) * 4;
#pragma unroll
        for (int nj = 0; nj < 4; ++nj) {
            const int col = n0 + wn + nj * 16 + lr;
            const int d   = col & 1023;
            const float bb = bias[col];
#pragma unroll
            for (int r = 0; r < 4; ++r) {
                float v = acc[mi][nj][r] + bb;
                const int idx = (rowb + r) * DIMV + d;
                if (gate == 0) {
                    gi[idx] = (_Float16)(10.0f * ftanh((v + ibias[d]) * 0.1f));
                } else if (gate == 1) {
                    gf[idx] = -fsoftplus(v);                           // log-forget
                } else if (gate == 2) {
                    go[idx] = (_Float16)fsig(v);                       // sigmoid
                } else {
                    gtz[idx] = (_Float16)ftanh(v);                     // tanh(z)
                }
            }
        }
    }
}

// ---------- chunked scan ----------
// pass1: per (channel, chunk) local scan from identity (m=-1e30): {F=sum f, M, c, n}
__global__ __launch_bounds__(256) void k_scan1(
    const _Float16* __restrict__ gi, const float* __restrict__ gf,
    const _Float16* __restrict__ gtz, float4* __restrict__ sums)
{
    const int ch = blockIdx.x * 256 + threadIdx.x;   // 0..4095
    const int chunk = blockIdx.y;
    const int b = ch >> 10, d = ch & 1023;
    int base = (b * TT + chunk * CL) * DIMV + d;
    float m = -1e30f, c = 0.0f, n = 0.0f, F = 0.0f;
#pragma unroll 4
    for (int t = 0; t < CL; ++t, base += DIMV) {
        const float iv = (float)gi[base];
        const float fv = gf[base];
        const float zv = (float)gtz[base];
        F += fv;
        const float mn = fmaxf(fv + m, iv);
        const float sc = __expf(fv + m - mn);
        const float si = __expf(iv - mn);
        c = sc * c + si * zv;
        n = sc * n + si;
        m = mn;
    }
    sums[chunk * 4096 + ch] = make_float4(F, m, c, n);
}

// pass2: sequential combine over chunks; emit incoming state per chunk
__global__ __launch_bounds__(256) void k_scan2(const float4* __restrict__ sums,
                                               float4* __restrict__ states) {
    const int ch = blockIdx.x * 256 + threadIdx.x;
    float m = -1e30f, c = 0.0f, n = 0.0f;
    for (int chunk = 0; chunk < NCH; ++chunk) {
        states[chunk * 4096 + ch] = make_float4(m, c, n, 0.0f);
        const float4 s = sums[chunk * 4096 + ch];
        const float mn = fmaxf(m + s.x, s.y);
        const float e1 = __expf(m + s.x - mn);
        const float e2 = __expf(s.y - mn);
        c = e1 * c + e2 * s.z;
        n = e1 * n + e2 * s.w;
        m = mn;
    }
}

// pass3: re-scan chunk from incoming state, emit h (fp16) into hbuf
__global__ __launch_bounds__(256) void k_scan3(
    const _Float16* __restrict__ gi, const float* __restrict__ gf,
    const _Float16* __restrict__ go, const _Float16* __restrict__ gtz,
    const float4* __restrict__ states, _Float16* __restrict__ hbuf)
{
    const int ch = blockIdx.x * 256 + threadIdx.x;
    const int chunk = blockIdx.y;
    const int b = ch >> 10, d = ch & 1023;
    int base = (b * TT + chunk * CL) * DIMV + d;
    const float4 st = states[chunk * 4096 + ch];
    float m = st.x, c = st.y, n = st.z;
#pragma unroll 4
    for (int t = 0; t < CL; ++t, base += DIMV) {
        const float iv = (float)gi[base];
        const float fv = gf[base];
        const float ov = (float)go[base];
        const float zv = (float)gtz[base];
        const float mn = fmaxf(fv + m, iv);
        const float sc = __expf(fv + m - mn);
        const float si = __expf(iv - mn);
        c = sc * c + si * zv;
        n = sc * n + si;
        m = mn;
        hbuf[base] = (_Float16)(ov * c / (n + 1e-6f));
    }
}

// ---------- RMSNorm: read h fp16, write fp32 out; one wave per 1024-row ----------
__global__ __launch_bounds__(256) void k_rmsnorm(const _Float16* __restrict__ h,
                                                 const float* __restrict__ scale,
                                                 float* __restrict__ out) {
    const int wid = threadIdx.x >> 6, lane = threadIdx.x & 63;
    const int row = blockIdx.x * 4 + wid;
    const half8* p = (const half8*)(h + (size_t)row * DIMV);  // 128 half8/row
    const float4* sc = (const float4*)scale;
    half8 v0 = p[lane * 2], v1 = p[lane * 2 + 1];             // 16 f16 per lane
    float f[16];
    float ss = 0.0f;
#pragma unroll
    for (int j = 0; j < 8; ++j) { f[j] = (float)v0[j]; f[8 + j] = (float)v1[j]; }
#pragma unroll
    for (int j = 0; j < 16; ++j) ss += f[j] * f[j];
#pragma unroll
    for (int off = 32; off > 0; off >>= 1) ss += __shfl_xor(ss, off, 64);
    const float inv = 1.0f / sqrtf(ss * (1.0f / 1024.0f) + 1e-8f);
    float4* po = (float4*)(out + (size_t)row * DIMV + lane * 16);
#pragma unroll
    for (int q = 0; q < 4; ++q) {
        const float4 s = sc[lane * 4 + q];
        float4 o;
        o.x = f[q * 4 + 0] * inv * s.x;
        o.y = f[q * 4 + 1] * inv * s.y;
        o.z = f[q * 4 + 2] * inv * s.z;
        o.w = f[q * 4 + 3] * inv * s.w;
        po[q] = o;
    }
}

extern "C" void kernel_launch(void* const* d_in, const int* in_sizes, int n_in,
                              void* d_out, int out_size, void* d_ws, size_t ws_size,
                              hipStream_t stream) {
    (void)in_sizes; (void)n_in; (void)out_size; (void)ws_size;
    const float* x     = (const float*)d_in[0];
    const float* W     = (const float*)d_in[1];
    const float* bias  = (const float*)d_in[2];
    const float* ibias = (const float*)d_in[3];
    const float* scale = (const float*)d_in[4];
    float* out = (float*)d_out;

    char* ws = (char*)d_ws;
    size_t off = 0;
    _Float16* Xs = (_Float16*)(ws + off); off += (size_t)MTOT * KK * 2;     //  33.5 MB
    _Float16* Wt = (_Float16*)(ws + off); off += (size_t)NCOL * KK * 2;     //   8.4 MB
    _Float16* gi = (_Float16*)(ws + off); off += (size_t)MTOT * DIMV * 2;   //  33.5 MB
    float*    gf = (float*)(ws + off);    off += (size_t)MTOT * DIMV * 4;   //  67.1 MB
    _Float16* go = (_Float16*)(ws + off); off += (size_t)MTOT * DIMV * 2;   //  33.5 MB
    _Float16* gtz= (_Float16*)(ws + off); off += (size_t)MTOT * DIMV * 2;   //  33.5 MB
    float4* sums   = (float4*)(ws + off); off += (size_t)NCH * 4096 * 16;   //   4.2 MB
    float4* states = (float4*)(ws + off); off += (size_t)NCH * 4096 * 16;   //   4.2 MB
    _Float16* hbuf = Xs;   // Xs is dead after the GEMM; reuse for h (33.5 MB)

    k_cvt_x<<<(MTOT * DIMV) / 256, 256, 0, stream>>>(x, Xs);
    k_cvt_w<<<dim3(NCOL / 32, KK / 32), 256, 0, stream>>>(W, Wt);
    k_gemm_gates<<<dim3(NCOL / BN, MTOT / BM), 256, 0, stream>>>(
        Xs, Wt, bias, ibias, gi, gf, go, gtz);
    k_scan1<<<dim3(16, NCH), 256, 0, stream>>>(gi, gf, gtz, sums);
    k_scan2<<<16, 256, 0, stream>>>(sums, states);
    k_scan3<<<dim3(16, NCH), 256, 0, stream>>>(gi, gf, go, gtz, states, hbuf);
    k_rmsnorm<<<MTOT / 4, 256, 0, stream>>>(hbuf, scale, out);
}

// Round 11
// 343.264 us; speedup vs baseline: 1.5809x; 1.5809x over previous
//
#include <hip/hip_runtime.h>
#include <cstdint>
#include <cstddef>

#define TT    4096          // sequence length
#define NB    4             // batch
#define DIMV  1024
#define MTOT  (NB*TT)       // 16384 rows
#define KK    1024          // GEMM K
#define NCOL  4096          // GEMM N (4*DIM)
#define NCH   64            // scan chunks
#define CL    (TT/NCH)      // 64 steps per chunk

#define BM 256
#define BN 256
#define BK 32

typedef _Float16 half8 __attribute__((ext_vector_type(8)));
typedef float    f32x4 __attribute__((ext_vector_type(4)));
typedef __attribute__((address_space(1))) void GV;
typedef __attribute__((address_space(3))) void LV;

__device__ __forceinline__ void gload16(const void* g, void* l) {
    __builtin_amdgcn_global_load_lds((GV*)g, (LV*)l, 16, 0, 0);
}

// fast activations: v_exp_f32 / v_log_f32 based, overflow-safe
__device__ __forceinline__ float ftanh(float x) {          // 1 - 2/(e^2x+1)
    return 1.0f - 2.0f / (__expf(2.0f * x) + 1.0f);
}
__device__ __forceinline__ float fsig(float x) {
    return 1.0f / (1.0f + __expf(-x));
}
__device__ __forceinline__ float fsoftplus(float x) {
    return fmaxf(x, 0.0f) + __logf(1.0f + __expf(-fabsf(x)));
}

// ---------- conversions ----------
__global__ __launch_bounds__(256) void k_cvt_x(const float* __restrict__ x,
                                               _Float16* __restrict__ Xs) {
    int idx = blockIdx.x * 256 + threadIdx.x;   // [16384][1024]
    Xs[idx] = (_Float16)x[idx];
}

// W [1024][4096] fp32 -> Wt [4096][1024] fp16 (transposed, N-major for B^T GEMM)
__global__ __launch_bounds__(256) void k_cvt_w(const float* __restrict__ W,
                                               _Float16* __restrict__ Wt) {
    __shared__ float tile[32][33];
    int tx = threadIdx.x & 31, ty = threadIdx.x >> 5;   // 32 x 8
    int nb = blockIdx.x * 32, kb = blockIdx.y * 32;
#pragma unroll
    for (int j = 0; j < 32; j += 8)
        tile[ty + j][tx] = W[(size_t)(kb + ty + j) * NCOL + nb + tx];
    __syncthreads();
#pragma unroll
    for (int j = 0; j < 32; j += 8)
        Wt[(size_t)(nb + ty + j) * KK + kb + tx] = (_Float16)tile[tx][ty + j];
}

// ---------- GEMM + fused gate activations (R6 structure, best measured) ----
// A = Xs [16384][1024] f16, Bt = Wt [4096][1024] f16 (both row-major).
// 256x256 tile, BK=32, 8 waves (2M x 4N), wave-tile 128x64 (8x4 frags of
// 16x16x32), acc 128 VGPR. 2-phase double-buffer: issue next tile's
// global_load_lds BEFORE the current tile's ds_read+MFMA; one __syncthreads
// per K-tile. LDS 2x32 KB. Anti-conflict swizzle (rule 21, 0 conflicts
// measured): phys 16B slot s of row r holds logical slot s ^ ((r>>1)&3);
// linear LDS dest, pre-swizzled global src, XOR on read.
__global__ __launch_bounds__(512) void k_gemm_gates(
    const _Float16* __restrict__ Xs, const _Float16* __restrict__ Wt,
    const float* __restrict__ bias, const float* __restrict__ ibias,
    _Float16* __restrict__ gi, _Float16* __restrict__ gf,
    _Float16* __restrict__ go, _Float16* __restrict__ gtz)
{
    __shared__ __align__(16) _Float16 Al0[BM * BK];   // 16 KB each
    __shared__ __align__(16) _Float16 Al1[BM * BK];
    __shared__ __align__(16) _Float16 Bl0[BN * BK];
    __shared__ __align__(16) _Float16 Bl1[BN * BK];
    const int tid  = threadIdx.x;       // 0..511
    const int lane = tid & 63;
    const int wave = tid >> 6;          // 0..7

    // bijective XCD swizzle (nwg = 1024, multiple of 8)
    const int nwg = 16 * 64;
    int id = blockIdx.y * 16 + blockIdx.x;
    id = (id & 7) * (nwg >> 3) + (id >> 3);
    const int m0 = (id / 16) * BM;
    const int n0 = (id % 16) * BN;
    const int wm = (wave >> 2) * 128;   // 0 | 128
    const int wn = (wave & 3) * 64;     // 0,64,128,192

    // staging: thread stages rows r0 and r0+128 (16B chunks), phys slot tid&3.
    const int r0  = tid >> 2;                        // 0..127
    const int swz = (tid & 3) ^ ((r0 >> 1) & 3);     // same for r0+128
    const _Float16* aSrc = Xs + (size_t)(m0 + r0) * KK + swz * 8;
    const _Float16* bSrc = Wt + (size_t)(n0 + r0) * KK + swz * 8;

    f32x4 acc[8][4] = {};
    const int lr = lane & 15;
    const int ps = ((lane >> 4) ^ ((lr >> 1) & 3)) * 8;   // phys slot on read

#define STAGE(SRC, BUF, kkc)                                               \
    gload16(SRC + (kkc), &BUF[tid * 8]);                                   \
    gload16(SRC + (size_t)128 * KK + (kkc), &BUF[tid * 8 + 4096]);

#define COMPUTE(ABUF, BBUF)                                                \
    {                                                                      \
        half8 af[8], bf[4];                                                \
        _Pragma("unroll")                                                  \
        for (int mi = 0; mi < 8; ++mi)                                     \
            af[mi] = *(const half8*)&ABUF[(wm + mi * 16 + lr) * BK + ps];  \
        _Pragma("unroll")                                                  \
        for (int nj = 0; nj < 4; ++nj)                                     \
            bf[nj] = *(const half8*)&BBUF[(wn + nj * 16 + lr) * BK + ps];  \
        __builtin_amdgcn_s_setprio(1);                                     \
        _Pragma("unroll")                                                  \
        for (int mi = 0; mi < 8; ++mi)                                     \
            _Pragma("unroll")                                              \
            for (int nj = 0; nj < 4; ++nj)                                 \
                acc[mi][nj] = __builtin_amdgcn_mfma_f32_16x16x32_f16(      \
                    af[mi], bf[nj], acc[mi][nj], 0, 0, 0);                 \
        __builtin_amdgcn_s_setprio(0);                                     \
    }

    // prologue: tile 0 -> buf0
    STAGE(aSrc, Al0, 0) STAGE(bSrc, Bl0, 0)
    __syncthreads();
#pragma unroll 1
    for (int t = 0; t < 15; ++t) {
        const int k1 = (2 * t + 1) * BK, k2 = (2 * t + 2) * BK;
        STAGE(aSrc, Al1, k1) STAGE(bSrc, Bl1, k1)   // issue tile 2t+1 loads
        COMPUTE(Al0, Bl0)                           // compute tile 2t
        __syncthreads();                            // buf1 landed; buf0 reads done
        STAGE(aSrc, Al0, k2) STAGE(bSrc, Bl0, k2)   // issue tile 2t+2 loads
        COMPUTE(Al1, Bl1)                           // compute tile 2t+1
        __syncthreads();
    }
    {
        const int k1 = 31 * BK;
        STAGE(aSrc, Al1, k1) STAGE(bSrc, Bl1, k1)
        COMPUTE(Al0, Bl0)                           // tile 30
        __syncthreads();
        COMPUTE(Al1, Bl1)                           // tile 31
    }
#undef STAGE
#undef COMPUTE

    // epilogue: C/D layout col=lane&15, row=(lane>>4)*4+reg  [m89-verified]
    const int gate = n0 >> 10;          // block-uniform (256 | 1024)
#pragma unroll
    for (int mi = 0; mi < 8; ++mi) {
        const int rowb = m0 + wm + mi * 16 + (lane >> 4) * 4;
#pragma unroll
        for (int nj = 0; nj < 4; ++nj) {
            const int col = n0 + wn + nj * 16 + lr;
            const int d   = col & 1023;
            const float bb = bias[col];
#pragma unroll
            for (int r = 0; r < 4; ++r) {
                float v = acc[mi][nj][r] + bb;
                const int idx = (rowb + r) * DIMV + d;
                if (gate == 0) {
                    gi[idx] = (_Float16)(10.0f * ftanh((v + ibias[d]) * 0.1f));
                } else if (gate == 1) {
                    gf[idx] = (_Float16)(-fsoftplus(v));               // log-forget
                } else if (gate == 2) {
                    go[idx] = (_Float16)fsig(v);                       // sigmoid
                } else {
                    gtz[idx] = (_Float16)ftanh(v);                     // tanh(z)
                }
            }
        }
    }
}

// ---------- chunked scan ----------
// pass1: per (channel, chunk) local scan from identity (m=-1e30): {F=sum f, M, c, n}
__global__ __launch_bounds__(256) void k_scan1(
    const _Float16* __restrict__ gi, const _Float16* __restrict__ gf,
    const _Float16* __restrict__ gtz, float4* __restrict__ sums)
{
    const int ch = blockIdx.x * 256 + threadIdx.x;   // 0..4095
    const int chunk = blockIdx.y;
    const int b = ch >> 10, d = ch & 1023;
    int base = (b * TT + chunk * CL) * DIMV + d;
    float m = -1e30f, c = 0.0f, n = 0.0f, F = 0.0f;
#pragma unroll 4
    for (int t = 0; t < CL; ++t, base += DIMV) {
        const float iv = (float)gi[base];
        const float fv = (float)gf[base];
        const float zv = (float)gtz[base];
        F += fv;
        const float mn = fmaxf(fv + m, iv);
        const float sc = __expf(fv + m - mn);
        const float si = __expf(iv - mn);
        c = sc * c + si * zv;
        n = sc * n + si;
        m = mn;
    }
    sums[chunk * 4096 + ch] = make_float4(F, m, c, n);
}

// pass2: sequential combine over chunks; emit incoming state per chunk
__global__ __launch_bounds__(256) void k_scan2(const float4* __restrict__ sums,
                                               float4* __restrict__ states) {
    const int ch = blockIdx.x * 256 + threadIdx.x;
    float m = -1e30f, c = 0.0f, n = 0.0f;
    for (int chunk = 0; chunk < NCH; ++chunk) {
        states[chunk * 4096 + ch] = make_float4(m, c, n, 0.0f);
        const float4 s = sums[chunk * 4096 + ch];
        const float mn = fmaxf(m + s.x, s.y);
        const float e1 = __expf(m + s.x - mn);
        const float e2 = __expf(s.y - mn);
        c = e1 * c + e2 * s.z;
        n = e1 * n + e2 * s.w;
        m = mn;
    }
}

// pass3: re-scan chunk from incoming state, emit h (fp16) into hbuf
__global__ __launch_bounds__(256) void k_scan3(
    const _Float16* __restrict__ gi, const _Float16* __restrict__ gf,
    const _Float16* __restrict__ go, const _Float16* __restrict__ gtz,
    const float4* __restrict__ states, _Float16* __restrict__ hbuf)
{
    const int ch = blockIdx.x * 256 + threadIdx.x;
    const int chunk = blockIdx.y;
    const int b = ch >> 10, d = ch & 1023;
    int base = (b * TT + chunk * CL) * DIMV + d;
    const float4 st = states[chunk * 4096 + ch];
    float m = st.x, c = st.y, n = st.z;
#pragma unroll 4
    for (int t = 0; t < CL; ++t, base += DIMV) {
        const float iv = (float)gi[base];
        const float fv = (float)gf[base];
        const float ov = (float)go[base];
        const float zv = (float)gtz[base];
        const float mn = fmaxf(fv + m, iv);
        const float sc = __expf(fv + m - mn);
        const float si = __expf(iv - mn);
        c = sc * c + si * zv;
        n = sc * n + si;
        m = mn;
        hbuf[base] = (_Float16)(ov * c / (n + 1e-6f));
    }
}

// ---------- RMSNorm: read h fp16, write fp32 out; one wave per 1024-row ----------
__global__ __launch_bounds__(256) void k_rmsnorm(const _Float16* __restrict__ h,
                                                 const float* __restrict__ scale,
                                                 float* __restrict__ out) {
    const int wid = threadIdx.x >> 6, lane = threadIdx.x & 63;
    const int row = blockIdx.x * 4 + wid;
    const half8* p = (const half8*)(h + (size_t)row * DIMV);  // 128 half8/row
    const float4* sc = (const float4*)scale;
    half8 v0 = p[lane * 2], v1 = p[lane * 2 + 1];             // 16 f16 per lane
    float f[16];
    float ss = 0.0f;
#pragma unroll
    for (int j = 0; j < 8; ++j) { f[j] = (float)v0[j]; f[8 + j] = (float)v1[j]; }
#pragma unroll
    for (int j = 0; j < 16; ++j) ss += f[j] * f[j];
#pragma unroll
    for (int off = 32; off > 0; off >>= 1) ss += __shfl_xor(ss, off, 64);
    const float inv = 1.0f / sqrtf(ss * (1.0f / 1024.0f) + 1e-8f);
    float4* po = (float4*)(out + (size_t)row * DIMV + lane * 16);
#pragma unroll
    for (int q = 0; q < 4; ++q) {
        const float4 s = sc[lane * 4 + q];
        float4 o;
        o.x = f[q * 4 + 0] * inv * s.x;
        o.y = f[q * 4 + 1] * inv * s.y;
        o.z = f[q * 4 + 2] * inv * s.z;
        o.w = f[q * 4 + 3] * inv * s.w;
        po[q] = o;
    }
}

extern "C" void kernel_launch(void* const* d_in, const int* in_sizes, int n_in,
                              void* d_out, int out_size, void* d_ws, size_t ws_size,
                              hipStream_t stream) {
    (void)in_sizes; (void)n_in; (void)out_size; (void)ws_size;
    const float* x     = (const float*)d_in[0];
    const float* W     = (const float*)d_in[1];
    const float* bias  = (const float*)d_in[2];
    const float* ibias = (const float*)d_in[3];
    const float* scale = (const float*)d_in[4];
    float* out = (float*)d_out;

    char* ws = (char*)d_ws;
    size_t off = 0;
    _Float16* Xs = (_Float16*)(ws + off); off += (size_t)MTOT * KK * 2;     //  33.5 MB
    _Float16* Wt = (_Float16*)(ws + off); off += (size_t)NCOL * KK * 2;     //   8.4 MB
    _Float16* gi = (_Float16*)(ws + off); off += (size_t)MTOT * DIMV * 2;   //  33.5 MB
    _Float16* gf = (_Float16*)(ws + off); off += (size_t)MTOT * DIMV * 2;   //  33.5 MB
    _Float16* go = (_Float16*)(ws + off); off += (size_t)MTOT * DIMV * 2;   //  33.5 MB
    _Float16* gtz= (_Float16*)(ws + off); off += (size_t)MTOT * DIMV * 2;   //  33.5 MB
    float4* sums   = (float4*)(ws + off); off += (size_t)NCH * 4096 * 16;   //   4.2 MB
    float4* states = (float4*)(ws + off); off += (size_t)NCH * 4096 * 16;   //   4.2 MB
    _Float16* hbuf = Xs;   // Xs is dead after the GEMM; reuse for h (33.5 MB)

    k_cvt_x<<<(MTOT * DIMV) / 256, 256, 0, stream>>>(x, Xs);
    k_cvt_w<<<dim3(NCOL / 32, KK / 32), 256, 0, stream>>>(W, Wt);
    k_gemm_gates<<<dim3(NCOL / BN, MTOT / BM), 512, 0, stream>>>(
        Xs, Wt, bias, ibias, gi, gf, go, gtz);
    k_scan1<<<dim3(16, NCH), 256, 0, stream>>>(gi, gf, gtz, sums);
    k_scan2<<<16, 256, 0, stream>>>(sums, states);
    k_scan3<<<dim3(16, NCH), 256, 0, stream>>>(gi, gf, go, gtz, states, hbuf);
    k_rmsnorm<<<MTOT / 4, 256, 0, stream>>>(hbuf, scale, out);
}

// Round 12
// 260.149 us; speedup vs baseline: 2.0860x; 1.3195x over previous
//
#include <hip/hip_runtime.h>
#include <cstdint>
#include <cstddef>

#define TT    4096          // sequence length
#define NB    4             // batch
#define DIMV  1024
#define MTOT  (NB*TT)       // 16384 rows
#define KK    1024          // GEMM K
#define NCOL  4096          // GEMM N (4*DIM)
#define NCH   64            // scan chunks
#define CL    (TT/NCH)      // 64 steps per chunk

#define BM 256
#define BN 256
#define BK 32

// Tiled gate layout: element (t,d) lives at (t>>3)*8192 + d*8 + (t&7).
// 8 consecutive timesteps of one channel = one 16B half8.

typedef _Float16 half4 __attribute__((ext_vector_type(4)));
typedef _Float16 half8 __attribute__((ext_vector_type(8)));
typedef float    f32x4 __attribute__((ext_vector_type(4)));
typedef __attribute__((address_space(1))) void GV;
typedef __attribute__((address_space(3))) void LV;

__device__ __forceinline__ void gload16(const void* g, void* l) {
    __builtin_amdgcn_global_load_lds((GV*)g, (LV*)l, 16, 0, 0);
}

// fast activations: v_exp_f32 / v_log_f32 based, overflow-safe
__device__ __forceinline__ float ftanh(float x) {          // 1 - 2/(e^2x+1)
    return 1.0f - 2.0f / (__expf(2.0f * x) + 1.0f);
}
__device__ __forceinline__ float fsig(float x) {
    return 1.0f / (1.0f + __expf(-x));
}
__device__ __forceinline__ float fsoftplus(float x) {
    return fmaxf(x, 0.0f) + __logf(1.0f + __expf(-fabsf(x)));
}

// ---------- conversions ----------
__global__ __launch_bounds__(256) void k_cvt_x(const float* __restrict__ x,
                                               _Float16* __restrict__ Xs) {
    const size_t i = ((size_t)blockIdx.x * 256 + threadIdx.x) * 8;
    const float4 a = *(const float4*)&x[i];
    const float4 b = *(const float4*)&x[i + 4];
    half8 o;
    o[0] = (_Float16)a.x; o[1] = (_Float16)a.y;
    o[2] = (_Float16)a.z; o[3] = (_Float16)a.w;
    o[4] = (_Float16)b.x; o[5] = (_Float16)b.y;
    o[6] = (_Float16)b.z; o[7] = (_Float16)b.w;
    *(half8*)&Xs[i] = o;
}

// W [1024][4096] fp32 -> Wt [4096][1024] fp16 (transposed, N-major for B^T GEMM)
__global__ __launch_bounds__(256) void k_cvt_w(const float* __restrict__ W,
                                               _Float16* __restrict__ Wt) {
    __shared__ float tile[32][33];
    int tx = threadIdx.x & 31, ty = threadIdx.x >> 5;   // 32 x 8
    int nb = blockIdx.x * 32, kb = blockIdx.y * 32;
#pragma unroll
    for (int j = 0; j < 32; j += 8)
        tile[ty + j][tx] = W[(size_t)(kb + ty + j) * NCOL + nb + tx];
    __syncthreads();
#pragma unroll
    for (int j = 0; j < 32; j += 8)
        Wt[(size_t)(nb + ty + j) * KK + kb + tx] = (_Float16)tile[tx][ty + j];
}

// ---------- GEMM + fused gate activations (R6 structure, best measured) ----
// A = Xs [16384][1024] f16, Bt = Wt [4096][1024] f16 (both row-major).
// 256x256 tile, BK=32, 8 waves (2M x 4N), wave-tile 128x64, acc 128 VGPR.
// 2-phase double-buffer, one __syncthreads per K-tile, LDS 2x32 KB.
// Anti-conflict swizzle (rule 21, 0 conflicts measured).
// Epilogue writes gates in TILED layout via one half4 store per (mi,nj)
// (the 4 r-values are consecutive: rowb&7 in {0,4}).
__global__ __launch_bounds__(512) void k_gemm_gates(
    const _Float16* __restrict__ Xs, const _Float16* __restrict__ Wt,
    const float* __restrict__ bias, const float* __restrict__ ibias,
    _Float16* __restrict__ gi, _Float16* __restrict__ gf,
    _Float16* __restrict__ go, _Float16* __restrict__ gtz)
{
    __shared__ __align__(16) _Float16 Al0[BM * BK];   // 16 KB each
    __shared__ __align__(16) _Float16 Al1[BM * BK];
    __shared__ __align__(16) _Float16 Bl0[BN * BK];
    __shared__ __align__(16) _Float16 Bl1[BN * BK];
    const int tid  = threadIdx.x;       // 0..511
    const int lane = tid & 63;
    const int wave = tid >> 6;          // 0..7

    // bijective XCD swizzle (nwg = 1024, multiple of 8)
    const int nwg = 16 * 64;
    int id = blockIdx.y * 16 + blockIdx.x;
    id = (id & 7) * (nwg >> 3) + (id >> 3);
    const int m0 = (id / 16) * BM;
    const int n0 = (id % 16) * BN;
    const int wm = (wave >> 2) * 128;   // 0 | 128
    const int wn = (wave & 3) * 64;     // 0,64,128,192

    // staging: thread stages rows r0 and r0+128 (16B chunks), phys slot tid&3.
    const int r0  = tid >> 2;                        // 0..127
    const int swz = (tid & 3) ^ ((r0 >> 1) & 3);     // same for r0+128
    const _Float16* aSrc = Xs + (size_t)(m0 + r0) * KK + swz * 8;
    const _Float16* bSrc = Wt + (size_t)(n0 + r0) * KK + swz * 8;

    f32x4 acc[8][4] = {};
    const int lr = lane & 15;
    const int ps = ((lane >> 4) ^ ((lr >> 1) & 3)) * 8;   // phys slot on read

#define STAGE(SRC, BUF, kkc)                                               \
    gload16(SRC + (kkc), &BUF[tid * 8]);                                   \
    gload16(SRC + (size_t)128 * KK + (kkc), &BUF[tid * 8 + 4096]);

#define COMPUTE(ABUF, BBUF)                                                \
    {                                                                      \
        half8 af[8], bf[4];                                                \
        _Pragma("unroll")                                                  \
        for (int mi = 0; mi < 8; ++mi)                                     \
            af[mi] = *(const half8*)&ABUF[(wm + mi * 16 + lr) * BK + ps];  \
        _Pragma("unroll")                                                  \
        for (int nj = 0; nj < 4; ++nj)                                     \
            bf[nj] = *(const half8*)&BBUF[(wn + nj * 16 + lr) * BK + ps];  \
        __builtin_amdgcn_s_setprio(1);                                     \
        _Pragma("unroll")                                                  \
        for (int mi = 0; mi < 8; ++mi)                                     \
            _Pragma("unroll")                                              \
            for (int nj = 0; nj < 4; ++nj)                                 \
                acc[mi][nj] = __builtin_amdgcn_mfma_f32_16x16x32_f16(      \
                    af[mi], bf[nj], acc[mi][nj], 0, 0, 0);                 \
        __builtin_amdgcn_s_setprio(0);                                     \
    }

    // prologue: tile 0 -> buf0
    STAGE(aSrc, Al0, 0) STAGE(bSrc, Bl0, 0)
    __syncthreads();
#pragma unroll 1
    for (int t = 0; t < 15; ++t) {
        const int k1 = (2 * t + 1) * BK, k2 = (2 * t + 2) * BK;
        STAGE(aSrc, Al1, k1) STAGE(bSrc, Bl1, k1)   // issue tile 2t+1 loads
        COMPUTE(Al0, Bl0)                           // compute tile 2t
        __syncthreads();                            // buf1 landed; buf0 reads done
        STAGE(aSrc, Al0, k2) STAGE(bSrc, Bl0, k2)   // issue tile 2t+2 loads
        COMPUTE(Al1, Bl1)                           // compute tile 2t+1
        __syncthreads();
    }
    {
        const int k1 = 31 * BK;
        STAGE(aSrc, Al1, k1) STAGE(bSrc, Bl1, k1)
        COMPUTE(Al0, Bl0)                           // tile 30
        __syncthreads();
        COMPUTE(Al1, Bl1)                           // tile 31
    }
#undef STAGE
#undef COMPUTE

    // epilogue: C/D layout col=lane&15, row=(lane>>4)*4+reg  [m89-verified]
    const int gate = n0 >> 10;          // block-uniform (256 | 1024)
#pragma unroll
    for (int mi = 0; mi < 8; ++mi) {
        const int rowb  = m0 + wm + mi * 16 + (lane >> 4) * 4;
        const int abase = (rowb >> 3) * 8192 + (rowb & 7);   // tiled layout base
#pragma unroll
        for (int nj = 0; nj < 4; ++nj) {
            const int col = n0 + wn + nj * 16 + lr;
            const int d   = col & 1023;
            const float bb = bias[col];
            float v[4];
#pragma unroll
            for (int r = 0; r < 4; ++r) v[r] = acc[mi][nj][r] + bb;
            half4 o;
            if (gate == 0) {
                const float ib = ibias[d];
#pragma unroll
                for (int r = 0; r < 4; ++r)
                    o[r] = (_Float16)(10.0f * ftanh((v[r] + ib) * 0.1f));
                *(half4*)&gi[abase + d * 8] = o;
            } else if (gate == 1) {
#pragma unroll
                for (int r = 0; r < 4; ++r)
                    o[r] = (_Float16)(-fsoftplus(v[r]));
                *(half4*)&gf[abase + d * 8] = o;
            } else if (gate == 2) {
#pragma unroll
                for (int r = 0; r < 4; ++r)
                    o[r] = (_Float16)fsig(v[r]);
                *(half4*)&go[abase + d * 8] = o;
            } else {
#pragma unroll
                for (int r = 0; r < 4; ++r)
                    o[r] = (_Float16)ftanh(v[r]);
                *(half4*)&gtz[abase + d * 8] = o;
            }
        }
    }
}

// ---------- chunked scan (tiled gate layout: half8 = 8 timesteps/load) ----------
// pass1: per (channel, chunk) local scan from identity (m=-1e30): {F=sum f, M, c, n}
__global__ __launch_bounds__(256) void k_scan1(
    const _Float16* __restrict__ gi, const _Float16* __restrict__ gf,
    const _Float16* __restrict__ gtz, float4* __restrict__ sums)
{
    const int ch = blockIdx.x * 256 + threadIdx.x;   // 0..4095
    const int chunk = blockIdx.y;
    const int b = ch >> 10, d = ch & 1023;
    size_t base = (size_t)(b * 512 + chunk * 8) * 8192 + d * 8;
    float m = -1e30f, c = 0.0f, n = 0.0f, F = 0.0f;
#pragma unroll 2
    for (int t8 = 0; t8 < 8; ++t8, base += 8192) {
        const half8 i8 = *(const half8*)&gi[base];
        const half8 f8 = *(const half8*)&gf[base];
        const half8 z8 = *(const half8*)&gtz[base];
#pragma unroll
        for (int j = 0; j < 8; ++j) {
            const float iv = (float)i8[j];
            const float fv = (float)f8[j];
            const float zv = (float)z8[j];
            F += fv;
            const float mn = fmaxf(fv + m, iv);
            const float sc = __expf(fv + m - mn);
            const float si = __expf(iv - mn);
            c = sc * c + si * zv;
            n = sc * n + si;
            m = mn;
        }
    }
    sums[chunk * 4096 + ch] = make_float4(F, m, c, n);
}

// pass2: sequential combine over chunks; emit incoming state per chunk
__global__ __launch_bounds__(256) void k_scan2(const float4* __restrict__ sums,
                                               float4* __restrict__ states) {
    const int ch = blockIdx.x * 256 + threadIdx.x;
    float m = -1e30f, c = 0.0f, n = 0.0f;
    for (int chunk = 0; chunk < NCH; ++chunk) {
        states[chunk * 4096 + ch] = make_float4(m, c, n, 0.0f);
        const float4 s = sums[chunk * 4096 + ch];
        const float mn = fmaxf(m + s.x, s.y);
        const float e1 = __expf(m + s.x - mn);
        const float e2 = __expf(s.y - mn);
        c = e1 * c + e2 * s.z;
        n = e1 * n + e2 * s.w;
        m = mn;
    }
}

// pass3: re-scan chunk from incoming state, emit h (fp16, tiled) into hbuf
__global__ __launch_bounds__(256) void k_scan3(
    const _Float16* __restrict__ gi, const _Float16* __restrict__ gf,
    const _Float16* __restrict__ go, const _Float16* __restrict__ gtz,
    const float4* __restrict__ states, _Float16* __restrict__ hbuf)
{
    const int ch = blockIdx.x * 256 + threadIdx.x;
    const int chunk = blockIdx.y;
    const int b = ch >> 10, d = ch & 1023;
    size_t base = (size_t)(b * 512 + chunk * 8) * 8192 + d * 8;
    const float4 st = states[chunk * 4096 + ch];
    float m = st.x, c = st.y, n = st.z;
#pragma unroll 2
    for (int t8 = 0; t8 < 8; ++t8, base += 8192) {
        const half8 i8 = *(const half8*)&gi[base];
        const half8 f8 = *(const half8*)&gf[base];
        const half8 o8 = *(const half8*)&go[base];
        const half8 z8 = *(const half8*)&gtz[base];
        half8 h8;
#pragma unroll
        for (int j = 0; j < 8; ++j) {
            const float iv = (float)i8[j];
            const float fv = (float)f8[j];
            const float ov = (float)o8[j];
            const float zv = (float)z8[j];
            const float mn = fmaxf(fv + m, iv);
            const float sc = __expf(fv + m - mn);
            const float si = __expf(iv - mn);
            c = sc * c + si * zv;
            n = sc * n + si;
            m = mn;
            h8[j] = (_Float16)(ov * c / (n + 1e-6f));
        }
        *(half8*)&hbuf[base] = h8;
    }
}

// ---------- RMSNorm: one block per 8-row tile of tiled h; fp32 out ----------
__global__ __launch_bounds__(256) void k_rmsnorm(const _Float16* __restrict__ h,
                                                 const float* __restrict__ scale,
                                                 float* __restrict__ out) {
    const int tb  = blockIdx.x;          // 0..2047 (8-row tiles)
    const int tid = threadIdx.x;
    const int wid = tid >> 6, lane = tid & 63;
    const int d0  = tid * 4;             // 4 consecutive channels per thread
    const size_t tbase = (size_t)tb * 8192;

    float hv[4][8];
    float s[8] = {0, 0, 0, 0, 0, 0, 0, 0};
#pragma unroll
    for (int q = 0; q < 4; ++q) {
        const half8 v = *(const half8*)&h[tbase + (size_t)(d0 + q) * 8];
#pragma unroll
        for (int j = 0; j < 8; ++j) {
            hv[q][j] = (float)v[j];
            s[j] += hv[q][j] * hv[q][j];
        }
    }
#pragma unroll
    for (int j = 0; j < 8; ++j)
#pragma unroll
        for (int off = 32; off > 0; off >>= 1)
            s[j] += __shfl_xor(s[j], off, 64);

    __shared__ float red[4][8];
    if (lane == 0) {
#pragma unroll
        for (int j = 0; j < 8; ++j) red[wid][j] = s[j];
    }
    __syncthreads();
    float inv[8];
#pragma unroll
    for (int j = 0; j < 8; ++j)
        inv[j] = rsqrtf((red[0][j] + red[1][j] + red[2][j] + red[3][j]) *
                        (1.0f / 1024.0f) + 1e-8f);

    const float4 sc = *(const float4*)&scale[d0];
#pragma unroll
    for (int j = 0; j < 8; ++j) {
        float4 o;
        o.x = hv[0][j] * inv[j] * sc.x;
        o.y = hv[1][j] * inv[j] * sc.y;
        o.z = hv[2][j] * inv[j] * sc.z;
        o.w = hv[3][j] * inv[j] * sc.w;
        *(float4*)&out[(size_t)(tb * 8 + j) * 1024 + d0] = o;
    }
}

extern "C" void kernel_launch(void* const* d_in, const int* in_sizes, int n_in,
                              void* d_out, int out_size, void* d_ws, size_t ws_size,
                              hipStream_t stream) {
    (void)in_sizes; (void)n_in; (void)out_size; (void)ws_size;
    const float* x     = (const float*)d_in[0];
    const float* W     = (const float*)d_in[1];
    const float* bias  = (const float*)d_in[2];
    const float* ibias = (const float*)d_in[3];
    const float* scale = (const float*)d_in[4];
    float* out = (float*)d_out;

    char* ws = (char*)d_ws;
    size_t off = 0;
    _Float16* Xs = (_Float16*)(ws + off); off += (size_t)MTOT * KK * 2;     //  33.5 MB
    _Float16* Wt = (_Float16*)(ws + off); off += (size_t)NCOL * KK * 2;     //   8.4 MB
    _Float16* gi = (_Float16*)(ws + off); off += (size_t)MTOT * DIMV * 2;   //  33.5 MB
    _Float16* gf = (_Float16*)(ws + off); off += (size_t)MTOT * DIMV * 2;   //  33.5 MB
    _Float16* go = (_Float16*)(ws + off); off += (size_t)MTOT * DIMV * 2;   //  33.5 MB
    _Float16* gtz= (_Float16*)(ws + off); off += (size_t)MTOT * DIMV * 2;   //  33.5 MB
    float4* sums   = (float4*)(ws + off); off += (size_t)NCH * 4096 * 16;   //   4.2 MB
    float4* states = (float4*)(ws + off); off += (size_t)NCH * 4096 * 16;   //   4.2 MB
    _Float16* hbuf = Xs;   // Xs is dead after the GEMM; reuse for h (33.5 MB)

    k_cvt_x<<<(MTOT * DIMV) / (256 * 8), 256, 0, stream>>>(x, Xs);
    k_cvt_w<<<dim3(NCOL / 32, KK / 32), 256, 0, stream>>>(W, Wt);
    k_gemm_gates<<<dim3(NCOL / BN, MTOT / BM), 512, 0, stream>>>(
        Xs, Wt, bias, ibias, gi, gf, go, gtz);
    k_scan1<<<dim3(16, NCH), 256, 0, stream>>>(gi, gf, gtz, sums);
    k_scan2<<<16, 256, 0, stream>>>(sums, states);
    k_scan3<<<dim3(16, NCH), 256, 0, stream>>>(gi, gf, go, gtz, states, hbuf);
    k_rmsnorm<<<MTOT / 8, 256, 0, stream>>>(hbuf, scale, out);
}